// Round 3
// baseline (5167.125 us; speedup 1.0000x reference)
//
#include <hip/hip_runtime.h>
#include <stdint.h>

// ---------------- ALL-F32 pipeline (CDNA4 has no f32 MFMA; vector FMA) ----------------
// Workspace layout (f32):
//   qkeyT [16][256][1024]   off 0         16,777,216 B
//   mkeyT [16][256][1024]   off 16777216  16,777,216 B
//   mval  [16][512][1024]   off 33554432  33,554,432 B
//   wattn [16][1024][1024]  off 67108864  67,108,864 B
// total 134,217,728 B (128 MB)
#define OFF_QKEYT 0ull
#define OFF_MKEYT 16777216ull
#define OFF_MVAL  33554432ull
#define OFF_WATTN 67108864ull

// ---------------- direct 3x3 conv, f32, NCHW in / channel-major out ----------------
// grid: x = m-chunk (48, 16 out-channels each), y = b (16). One block = one batch image,
// 16 output channels, all 1024 px. Each thread owns 4 px (t*4..t*4+3) x 16 channels.
__global__ __launch_bounds__(256) void k_conv(const float* __restrict__ x,
                                              const float* __restrict__ wk,   // [256][1024][9]
                                              const float* __restrict__ wv,   // [512][1024][9]
                                              const float* __restrict__ bk,   // [256]
                                              const float* __restrict__ bv,   // [512]
                                              float* __restrict__ keyT,       // [16][256][1024]
                                              float* __restrict__ valout,     // mval or d_out
                                              int vstride, int voffs) {
    int mc = blockIdx.x;          // 0..47
    int b  = blockIdx.y;
    int m0 = mc * 16;
    const float* wbase;
    const float* bias;
    float* outbase;
    if (m0 < 256) {
        wbase   = wk + (size_t)m0 * 9216;
        bias    = bk + m0;
        outbase = keyT + ((size_t)b * 256 + m0) * 1024;
    } else {
        int cv0 = m0 - 256;
        wbase   = wv + (size_t)cv0 * 9216;
        bias    = bv + cv0;
        outbase = valout + ((size_t)b * vstride + voffs + cv0) * 1024;
    }

    __shared__ float xs[34 * 34];   // padded plane, 4624 B
    int t = threadIdx.x;

    // zero the padded borders once (interior writes below never touch them)
    for (int i = t; i < 34 * 34; i += 256) {
        int y = i / 34, xx = i - y * 34;
        if (y == 0 || y == 33 || xx == 0 || xx == 33) xs[i] = 0.0f;
    }

    float acc[16][4];
    #pragma unroll
    for (int m = 0; m < 16; ++m)
        #pragma unroll
        for (int p = 0; p < 4; ++p) acc[m][p] = 0.0f;

    const float* xb = x + (size_t)b * 1024 * 1024;
    int py  = (t * 4) >> 5;        // output row of my 4 px
    int px0 = (t * 4) & 31;        // output col of px p=0
    __syncthreads();               // borders visible

    for (int c = 0; c < 1024; ++c) {
        float4 v4 = *(const float4*)(xb + (size_t)c * 1024 + t * 4);
        const float* wc = wbase + (size_t)c * 9;
        __syncthreads();           // previous iteration's reads done
        float* dst = &xs[(py + 1) * 34 + px0 + 1];
        dst[0] = v4.x; dst[1] = v4.y; dst[2] = v4.z; dst[3] = v4.w;
        __syncthreads();           // plane visible
        #pragma unroll
        for (int r = 0; r < 9; ++r) {
            int dy = r / 3, dx = r % 3;
            float wreg[16];
            #pragma unroll
            for (int m = 0; m < 16; ++m) wreg[m] = wc[(size_t)m * 9216 + r];
            #pragma unroll
            for (int p = 0; p < 4; ++p) {
                float v = xs[(py + dy) * 34 + px0 + p + dx];
                #pragma unroll
                for (int m = 0; m < 16; ++m) acc[m][p] += wreg[m] * v;
            }
        }
    }

    #pragma unroll
    for (int m = 0; m < 16; ++m) {
        float bm = bias[m];
        float4 o;
        o.x = acc[m][0] + bm; o.y = acc[m][1] + bm;
        o.z = acc[m][2] + bm; o.w = acc[m][3] + bm;
        *(float4*)(outbase + (size_t)m * 1024 + t * 4) = o;
    }
}

// ---------------- scores: wattn[b][q][m] = (sum_c mk[c][m]*qk[c][q]) / 16 ----------------
// grid (mt 16, qt 16, b 16); 256 thr: tx = t&15 (m dim), ty = t>>4 (q dim); 4x4 out each.
__global__ __launch_bounds__(256) void k_scores(const float* __restrict__ mkeyT,
                                                const float* __restrict__ qkeyT,
                                                float* __restrict__ wattn) {
    int mt = blockIdx.x, qt = blockIdx.y, b = blockIdx.z;
    __shared__ float As[8][64];   // mk rows (c-chunk)
    __shared__ float Bs[8][64];   // qk rows
    int t = threadIdx.x, tx = t & 15, ty = t >> 4;
    const float* mk = mkeyT + (size_t)b * 256 * 1024 + mt * 64;
    const float* qk = qkeyT + (size_t)b * 256 * 1024 + qt * 64;
    float acc[4][4];
    #pragma unroll
    for (int i = 0; i < 4; ++i)
        #pragma unroll
        for (int j = 0; j < 4; ++j) acc[i][j] = 0.0f;

    int half = t >> 7, idx = t & 127;          // 128 float4 per operand
    const float* stsrc = half ? qk : mk;
    for (int cc = 0; cc < 32; ++cc) {
        float4 v = *(const float4*)(stsrc + (size_t)(cc * 8 + (idx >> 4)) * 1024 + (idx & 15) * 4);
        __syncthreads();
        ((float4*)(half ? &Bs[0][0] : &As[0][0]))[idx] = v;
        __syncthreads();
        #pragma unroll
        for (int k = 0; k < 8; ++k) {
            float a[4], bb[4];
            #pragma unroll
            for (int i = 0; i < 4; ++i) a[i] = As[k][tx + 16 * i];
            #pragma unroll
            for (int j = 0; j < 4; ++j) bb[j] = Bs[k][ty + 16 * j];
            #pragma unroll
            for (int i = 0; i < 4; ++i)
                #pragma unroll
                for (int j = 0; j < 4; ++j) acc[i][j] += a[i] * bb[j];
        }
    }
    #pragma unroll
    for (int j = 0; j < 4; ++j) {
        int q = qt * 64 + ty + 16 * j;
        #pragma unroll
        for (int i = 0; i < 4; ++i) {
            int m = mt * 64 + tx + 16 * i;
            wattn[((size_t)b * 1024 + q) * 1024 + m] = acc[i][j] * 0.0625f;
        }
    }
}

// ---------------- softmax over m (rows of wattn[b][q][:]), f32 ----------------
__global__ __launch_bounds__(256) void k_softmax(float* __restrict__ wattn) {
    int row = blockIdx.x * 4 + (threadIdx.x >> 6);
    int l = threadIdx.x & 63;
    float* base = wattn + (size_t)row * 1024;
    float4 v[4];
    #pragma unroll
    for (int k = 0; k < 4; ++k) v[k] = *(float4*)(base + l * 4 + k * 256);
    float f[16];
    #pragma unroll
    for (int k = 0; k < 4; ++k) { f[4*k]=v[k].x; f[4*k+1]=v[k].y; f[4*k+2]=v[k].z; f[4*k+3]=v[k].w; }
    float mx = -3.0e38f;
    #pragma unroll
    for (int e = 0; e < 16; ++e) mx = fmaxf(mx, f[e]);
    #pragma unroll
    for (int off = 32; off > 0; off >>= 1) mx = fmaxf(mx, __shfl_xor(mx, off));
    float s = 0.0f;
    #pragma unroll
    for (int e = 0; e < 16; ++e) { f[e] = __expf(f[e] - mx); s += f[e]; }
    #pragma unroll
    for (int off = 32; off > 0; off >>= 1) s += __shfl_xor(s, off);
    float inv = 1.0f / s;
    #pragma unroll
    for (int k = 0; k < 4; ++k) {
        v[k].x = f[4*k] * inv; v[k].y = f[4*k+1] * inv;
        v[k].z = f[4*k+2] * inv; v[k].w = f[4*k+3] * inv;
        *(float4*)(base + l * 4 + k * 256) = v[k];
    }
}

// ---------------- PV: out[b][c][q] = sum_m mval[b][c][m] * wattn[b][q][m] ----------------
// grid (qt 16, ct 8, b 16); tx = t&15 (q dim), ty = t>>4 (c dim); 4x4 out each.
__global__ __launch_bounds__(256) void k_memv(const float* __restrict__ mval,
                                              const float* __restrict__ wattn,
                                              float* __restrict__ outp) {
    int qt = blockIdx.x, ct = blockIdx.y, b = blockIdx.z;
    __shared__ float Aw[64][17];   // wattn rows (q), 16 m + pad
    __shared__ float Bv[64][17];   // mval rows (c)
    int t = threadIdx.x, tx = t & 15, ty = t >> 4;
    const float* wv_ = wattn + ((size_t)b * 1024 + qt * 64) * 1024;
    const float* mv_ = mval + ((size_t)b * 512 + ct * 64) * 1024;
    float acc[4][4];
    #pragma unroll
    for (int i = 0; i < 4; ++i)
        #pragma unroll
        for (int j = 0; j < 4; ++j) acc[i][j] = 0.0f;

    int row = t >> 2, c4 = (t & 3) * 4;        // 256 float4 per operand
    for (int mm = 0; mm < 64; ++mm) {
        float4 va = *(const float4*)(wv_ + (size_t)row * 1024 + mm * 16 + c4);
        float4 vb = *(const float4*)(mv_ + (size_t)row * 1024 + mm * 16 + c4);
        __syncthreads();
        Aw[row][c4] = va.x; Aw[row][c4+1] = va.y; Aw[row][c4+2] = va.z; Aw[row][c4+3] = va.w;
        Bv[row][c4] = vb.x; Bv[row][c4+1] = vb.y; Bv[row][c4+2] = vb.z; Bv[row][c4+3] = vb.w;
        __syncthreads();
        #pragma unroll
        for (int k = 0; k < 16; ++k) {
            float a[4], bb[4];
            #pragma unroll
            for (int j = 0; j < 4; ++j) a[j] = Aw[tx + 16 * j][k];
            #pragma unroll
            for (int i = 0; i < 4; ++i) bb[i] = Bv[ty + 16 * i][k];
            #pragma unroll
            for (int i = 0; i < 4; ++i)
                #pragma unroll
                for (int j = 0; j < 4; ++j) acc[i][j] += bb[i] * a[j];
        }
    }
    #pragma unroll
    for (int i = 0; i < 4; ++i) {
        int cg = ct * 64 + ty + 16 * i;
        #pragma unroll
        for (int j = 0; j < 4; ++j) {
            int q = qt * 64 + tx + 16 * j;
            outp[((size_t)b * 1024 + cg) * 1024 + q] = acc[i][j];
        }
    }
}

extern "C" void kernel_launch(void* const* d_in, const int* in_sizes, int n_in,
                              void* d_out, int out_size, void* d_ws, size_t ws_size,
                              hipStream_t stream) {
    const float* src_temp   = (const float*)d_in[0];
    const float* src_search = (const float*)d_in[1];
    const float* wk_m = (const float*)d_in[2];
    const float* bk_m = (const float*)d_in[3];
    const float* wv_m = (const float*)d_in[4];
    const float* bv_m = (const float*)d_in[5];
    const float* wk_q = (const float*)d_in[6];
    const float* bk_q = (const float*)d_in[7];
    const float* wv_q = (const float*)d_in[8];
    const float* bv_q = (const float*)d_in[9];
    float* out = (float*)d_out;
    char* ws = (char*)d_ws;
    float* qkeyT = (float*)(ws + OFF_QKEYT);
    float* mkeyT = (float*)(ws + OFF_MKEYT);
    float* mval  = (float*)(ws + OFF_MVAL);
    float* wattn = (float*)(ws + OFF_WATTN);

    // conv for search (q): keys -> qkeyT, values -> d_out channels 512..1023
    hipLaunchKernelGGL(k_conv, dim3(48, 16), dim3(256), 0, stream,
                       src_search, wk_q, wv_q, bk_q, bv_q, qkeyT, out, 1024, 512);
    // conv for temp (m): keys -> mkeyT, values -> mval
    hipLaunchKernelGGL(k_conv, dim3(48, 16), dim3(256), 0, stream,
                       src_temp, wk_m, wv_m, bk_m, bv_m, mkeyT, mval, 512, 0);
    hipLaunchKernelGGL(k_scores,  dim3(16, 16, 16), dim3(256), 0, stream, mkeyT, qkeyT, wattn);
    hipLaunchKernelGGL(k_softmax, dim3(4096),       dim3(256), 0, stream, wattn);
    hipLaunchKernelGGL(k_memv,    dim3(16, 8, 16),  dim3(256), 0, stream, mval, wattn, out);
}

// Round 4
// 1897.770 us; speedup vs baseline: 2.7227x; 2.7227x over previous
//
#include <hip/hip_runtime.h>
#include <stdint.h>

typedef __bf16 bf16;
typedef __bf16 bf16x8 __attribute__((ext_vector_type(8)));
typedef float  f32x4  __attribute__((ext_vector_type(4)));

// ---------------- workspace layout (bytes), total = 134,217,728 (128 MB, proven) ----
// A: padded channel-last bf16 split X for 8 batches of ONE source (reused 4x)
//   A_hi [8][34][34][1024] bf16 : off 0          18,939,904 B
//   A_lo                        : off 18,939,904 18,939,904 B
// W: fragment-major split weights for ONE g (reused 2x)
//   W_hi [mt8][r9][cch32][coff4][mm96][e8] bf16 : off 37,879,808  14,155,776 B
//   W_lo                                        : off 52,035,584  14,155,776 B
// f32 intermediates:
//   qkeyT [16][256][1024] : off  67,108,864
//   mkeyT [16][256][1024] : off  83,886,080
//   mval  [16][512][1024] : off 100,663,296  (end 134,217,728)
//   wattn [16][1024][1024]: off 0 (67,108,864 B — overlays A+W, dead after convs)
#define OFF_AHI   0ull
#define OFF_ALO   18939904ull
#define OFF_WHI   37879808ull
#define OFF_WLO   52035584ull
#define OFF_QKEYT 67108864ull
#define OFF_MKEYT 83886080ull
#define OFF_MVAL  100663296ull
#define OFF_WATTN 0ull

__device__ __forceinline__ void split(float v, bf16& h, bf16& l) {
    h = (bf16)v;
    l = (bf16)(v - (float)h);
}

// ---------------- weight transform: fragment-major split ----------------
// Wt[mt][r][cch][coff][mm][e] <- w[m][c][r], m=mt*96+mm, c=cch*32+coff*8+e
__global__ __launch_bounds__(256) void k_wt(const float* __restrict__ wk,
                                            const float* __restrict__ wv,
                                            bf16* __restrict__ Wh, bf16* __restrict__ Wl) {
    size_t id = (size_t)blockIdx.x * 256 + threadIdx.x;   // < 7,077,888
    int e = (int)(id & 7);
    size_t t = id >> 3;
    int mm = (int)(t % 96); t /= 96;
    int coff = (int)(t & 3); t >>= 2;
    int cch = (int)(t & 31); t >>= 5;
    int r = (int)(t % 9);
    int mt = (int)(t / 9);
    int m = mt * 96 + mm;
    int c = cch * 32 + coff * 8 + e;
    float v = (m < 256) ? wk[((size_t)m * 1024 + c) * 9 + r]
                        : wv[((size_t)(m - 256) * 1024 + c) * 9 + r];
    bf16 h, l;
    split(v, h, l);
    Wh[id] = h; Wl[id] = l;
}

// ---------------- zero padded borders of A (once; interiors overwritten per reuse) ----
__global__ __launch_bounds__(256) void k_zero(bf16* __restrict__ Ah, bf16* __restrict__ Al) {
    int id = blockIdx.x * 256 + threadIdx.x;   // < 270,336
    int oct = id & 127;
    int t = id >> 7;
    int pos = t % 132; t /= 132;
    int bl = t & 7, hl = t >> 3;
    int yy, xx;
    if (pos < 34)       { yy = 0;  xx = pos; }
    else if (pos < 68)  { yy = 33; xx = pos - 34; }
    else if (pos < 100) { yy = pos - 68 + 1;  xx = 0; }
    else                { yy = pos - 100 + 1; xx = 33; }
    bf16* base = hl ? Al : Ah;
    size_t off = (((size_t)bl * 34 + yy) * 34 + xx) * 1024 + (size_t)oct * 8;
    *(uint4*)(base + off) = make_uint4(0u, 0u, 0u, 0u);
}

// ---------------- NCHW f32 -> padded channel-last bf16 hi/lo ----------------
// grid (pt16, ct16, bl8); src pre-offset to the 8-batch half.
__global__ __launch_bounds__(256) void k_transpose(const float* __restrict__ src,
                                                   bf16* __restrict__ Ah, bf16* __restrict__ Al) {
    int pt = blockIdx.x, ct = blockIdx.y, bl = blockIdx.z;
    __shared__ float tile[64][68];
    int t = threadIdx.x;
    #pragma unroll
    for (int k = 0; k < 4; ++k) {
        int idx = t + 256 * k;          // 0..1023
        int c = idx >> 4, f4 = idx & 15;
        float4 v = *(const float4*)(src + ((size_t)bl * 1024 + ct * 64 + c) * 1024 + pt * 64 + f4 * 4);
        *(float4*)&tile[c][f4 * 4] = v;
    }
    __syncthreads();
    #pragma unroll
    for (int k = 0; k < 2; ++k) {
        int s = t + 256 * k;            // 0..511
        int px = s >> 3, oct = s & 7;
        bf16x8 vh, vl;
        #pragma unroll
        for (int e = 0; e < 8; ++e) {
            bf16 h, l;
            split(tile[oct * 8 + e][px], h, l);
            vh[e] = h; vl[e] = l;
        }
        int pxg = pt * 64 + px;
        int yy = (pxg >> 5) + 1, xx = (pxg & 31) + 1;
        size_t off = (((size_t)bl * 34 + yy) * 34 + xx) * 1024 + ct * 64 + oct * 8;
        *(bf16x8*)(Ah + off) = vh;
        *(bf16x8*)(Al + off) = vl;
    }
}

// ---------------- conv: implicit GEMM, split-bf16 3-MFMA ----------------
// grid (x: bl8*8+rg, y: mt 0..7). Block: 96 out-ch x 128 px (4 rows).
// A-frags (weights) load straight from global (L2/L3-hot, fragment-major).
// B-frags (x) staged in LDS once per c-chunk, reused by all 9 taps.
#define XS_STRIDE 40   // 32 c used + 8 pad: 80B px-stride keeps 16B align, 2-way-max banks
__global__ __launch_bounds__(256) void k_conv(const bf16* __restrict__ Ah, const bf16* __restrict__ Al,
                                              const bf16* __restrict__ Wh, const bf16* __restrict__ Wl,
                                              const float* __restrict__ biask, const float* __restrict__ biasv,
                                              float* __restrict__ keyT, float* __restrict__ valout,
                                              int vstride, int voffs, int bglob) {
    int bl = blockIdx.x >> 3, rg = blockIdx.x & 7;
    int mt = blockIdx.y;
    int y0 = rg * 4;                    // padded rows y0..y0+5 -> out rows y0..y0+3
    int b = bglob + bl;

    __shared__ bf16 Xs[2 * 6 * 34 * XS_STRIDE];   // 32,640 B

    int tid = threadIdx.x;
    int w = tid >> 6, l = tid & 63;
    int wm = (w & 1) * 48, wn = (w >> 1) * 64;
    int lm = l & 15, lq = l >> 4;
    int koff = lq * 8;

    f32x4 acc[3][4] = {};

    const size_t Abase = ((size_t)bl * 34 + y0) * 34 * 1024;
    // per-lane invariant part of weight-frag address
    const size_t wlane = (size_t)lq * 768 + (size_t)lm * 8;

    for (int cch = 0; cch < 32; ++cch) {
        int c0 = cch * 32;
        // ---- load X window to VGPRs (1632 x 16B over 256 thr) ----
        bf16x8 xv[7];
        int lidx[7];
        #pragma unroll
        for (int it = 0; it < 7; ++it) {
            int s = tid + 256 * it;
            if (s < 1632) {
                int hl = s >= 816;
                int r816 = s - hl * 816;
                int row = r816 / 136;
                int rr = r816 - row * 136;
                int px = rr >> 2, oct = rr & 3;
                const bf16* base = hl ? Al : Ah;
                xv[it] = *(const bf16x8*)(base + Abase + ((size_t)row * 34 + px) * 1024 + c0 + oct * 8);
                lidx[it] = ((hl * 6 + row) * 34 + px) * XS_STRIDE + oct * 8;
            } else lidx[it] = -1;
        }
        __syncthreads();                // previous iteration's LDS reads complete
        #pragma unroll
        for (int it = 0; it < 7; ++it)
            if (lidx[it] >= 0) *(bf16x8*)&Xs[lidx[it]] = xv[it];
        __syncthreads();                // LDS visible

        // ---- 9 taps ----
        #pragma unroll
        for (int r = 0; r < 9; ++r) {
            int dy = r / 3, dx = r % 3;
            size_t wblk = (((size_t)mt * 9 + r) * 32 + cch) * 3072 + wlane;
            bf16x8 ah[3], al[3];
            #pragma unroll
            for (int i = 0; i < 3; ++i) {
                size_t o = wblk + (size_t)(wm + i * 16) * 8;
                ah[i] = *(const bf16x8*)(Wh + o);
                al[i] = *(const bf16x8*)(Wl + o);
            }
            #pragma unroll
            for (int j = 0; j < 4; ++j) {
                int n = wn + j * 16 + lm;
                int lbase = (((n >> 5) + dy) * 34 + (n & 31) + dx) * XS_STRIDE + koff;
                bf16x8 bh = *(const bf16x8*)&Xs[lbase];
                bf16x8 blo = *(const bf16x8*)&Xs[6 * 34 * XS_STRIDE + lbase];
                #pragma unroll
                for (int i = 0; i < 3; ++i) {
                    acc[i][j] = __builtin_amdgcn_mfma_f32_16x16x32_bf16(ah[i], bh,  acc[i][j], 0, 0, 0);
                    acc[i][j] = __builtin_amdgcn_mfma_f32_16x16x32_bf16(ah[i], blo, acc[i][j], 0, 0, 0);
                    acc[i][j] = __builtin_amdgcn_mfma_f32_16x16x32_bf16(al[i], bh,  acc[i][j], 0, 0, 0);
                }
            }
        }
    }

    // ---- epilogue: C/D layout col=lane&15, row=(lane>>4)*4+reg ----
    int col = lm, rowb = lq * 4;
    #pragma unroll
    for (int i = 0; i < 3; ++i) {
        int ch4 = mt * 96 + wm + i * 16 + rowb;   // 4 consecutive out-channels (no 256-straddle)
        #pragma unroll
        for (int j = 0; j < 4; ++j) {
            int px = rg * 128 + wn + j * 16 + col;
            if (ch4 < 256) {
                #pragma unroll
                for (int e = 0; e < 4; ++e)
                    keyT[((size_t)b * 256 + ch4 + e) * 1024 + px] = acc[i][j][e] + biask[ch4 + e];
            } else {
                int cv = ch4 - 256;
                #pragma unroll
                for (int e = 0; e < 4; ++e)
                    valout[((size_t)b * vstride + voffs + cv + e) * 1024 + px] = acc[i][j][e] + biasv[cv + e];
            }
        }
    }
}

// ---------------- scores: wattn[b][q][m] = (sum_c mk[c][m]*qk[c][q]) / 16 ----------------
__global__ __launch_bounds__(256) void k_scores(const float* __restrict__ mkeyT,
                                                const float* __restrict__ qkeyT,
                                                float* __restrict__ wattn) {
    int mt = blockIdx.x, qt = blockIdx.y, b = blockIdx.z;
    __shared__ float As[8][64];
    __shared__ float Bs[8][64];
    int t = threadIdx.x, tx = t & 15, ty = t >> 4;
    const float* mk = mkeyT + (size_t)b * 256 * 1024 + mt * 64;
    const float* qk = qkeyT + (size_t)b * 256 * 1024 + qt * 64;
    float acc[4][4];
    #pragma unroll
    for (int i = 0; i < 4; ++i)
        #pragma unroll
        for (int j = 0; j < 4; ++j) acc[i][j] = 0.0f;

    int half = t >> 7, idx = t & 127;
    const float* stsrc = half ? qk : mk;
    for (int cc = 0; cc < 32; ++cc) {
        float4 v = *(const float4*)(stsrc + (size_t)(cc * 8 + (idx >> 4)) * 1024 + (idx & 15) * 4);
        __syncthreads();
        ((float4*)(half ? &Bs[0][0] : &As[0][0]))[idx] = v;
        __syncthreads();
        #pragma unroll
        for (int k = 0; k < 8; ++k) {
            float a[4], bb[4];
            #pragma unroll
            for (int i = 0; i < 4; ++i) a[i] = As[k][tx + 16 * i];
            #pragma unroll
            for (int j = 0; j < 4; ++j) bb[j] = Bs[k][ty + 16 * j];
            #pragma unroll
            for (int i = 0; i < 4; ++i)
                #pragma unroll
                for (int j = 0; j < 4; ++j) acc[i][j] += a[i] * bb[j];
        }
    }
    #pragma unroll
    for (int j = 0; j < 4; ++j) {
        int q = qt * 64 + ty + 16 * j;
        #pragma unroll
        for (int i = 0; i < 4; ++i) {
            int m = mt * 64 + tx + 16 * i;
            wattn[((size_t)b * 1024 + q) * 1024 + m] = acc[i][j] * 0.0625f;
        }
    }
}

// ---------------- softmax over m ----------------
__global__ __launch_bounds__(256) void k_softmax(float* __restrict__ wattn) {
    int row = blockIdx.x * 4 + (threadIdx.x >> 6);
    int l = threadIdx.x & 63;
    float* base = wattn + (size_t)row * 1024;
    float4 v[4];
    #pragma unroll
    for (int k = 0; k < 4; ++k) v[k] = *(float4*)(base + l * 4 + k * 256);
    float f[16];
    #pragma unroll
    for (int k = 0; k < 4; ++k) { f[4*k]=v[k].x; f[4*k+1]=v[k].y; f[4*k+2]=v[k].z; f[4*k+3]=v[k].w; }
    float mx = -3.0e38f;
    #pragma unroll
    for (int e = 0; e < 16; ++e) mx = fmaxf(mx, f[e]);
    #pragma unroll
    for (int off = 32; off > 0; off >>= 1) mx = fmaxf(mx, __shfl_xor(mx, off));
    float s = 0.0f;
    #pragma unroll
    for (int e = 0; e < 16; ++e) { f[e] = __expf(f[e] - mx); s += f[e]; }
    #pragma unroll
    for (int off = 32; off > 0; off >>= 1) s += __shfl_xor(s, off);
    float inv = 1.0f / s;
    #pragma unroll
    for (int k = 0; k < 4; ++k) {
        v[k].x = f[4*k] * inv; v[k].y = f[4*k+1] * inv;
        v[k].z = f[4*k+2] * inv; v[k].w = f[4*k+3] * inv;
        *(float4*)(base + l * 4 + k * 256) = v[k];
    }
}

// ---------------- PV: out[b][c][q] = sum_m mval[b][c][m] * wattn[b][q][m] ----------------
__global__ __launch_bounds__(256) void k_memv(const float* __restrict__ mval,
                                              const float* __restrict__ wattn,
                                              float* __restrict__ outp) {
    int qt = blockIdx.x, ct = blockIdx.y, b = blockIdx.z;
    __shared__ float Aw[64][17];
    __shared__ float Bv[64][17];
    int t = threadIdx.x, tx = t & 15, ty = t >> 4;
    const float* wv_ = wattn + ((size_t)b * 1024 + qt * 64) * 1024;
    const float* mv_ = mval + ((size_t)b * 512 + ct * 64) * 1024;
    float acc[4][4];
    #pragma unroll
    for (int i = 0; i < 4; ++i)
        #pragma unroll
        for (int j = 0; j < 4; ++j) acc[i][j] = 0.0f;

    int row = t >> 2, c4 = (t & 3) * 4;
    for (int mm = 0; mm < 64; ++mm) {
        float4 va = *(const float4*)(wv_ + (size_t)row * 1024 + mm * 16 + c4);
        float4 vb = *(const float4*)(mv_ + (size_t)row * 1024 + mm * 16 + c4);
        __syncthreads();
        Aw[row][c4] = va.x; Aw[row][c4+1] = va.y; Aw[row][c4+2] = va.z; Aw[row][c4+3] = va.w;
        Bv[row][c4] = vb.x; Bv[row][c4+1] = vb.y; Bv[row][c4+2] = vb.z; Bv[row][c4+3] = vb.w;
        __syncthreads();
        #pragma unroll
        for (int k = 0; k < 16; ++k) {
            float a[4], bb[4];
            #pragma unroll
            for (int j = 0; j < 4; ++j) a[j] = Aw[tx + 16 * j][k];
            #pragma unroll
            for (int i = 0; i < 4; ++i) bb[i] = Bv[ty + 16 * i][k];
            #pragma unroll
            for (int i = 0; i < 4; ++i)
                #pragma unroll
                for (int j = 0; j < 4; ++j) acc[i][j] += bb[i] * a[j];
        }
    }
    #pragma unroll
    for (int i = 0; i < 4; ++i) {
        int cg = ct * 64 + ty + 16 * i;
        #pragma unroll
        for (int j = 0; j < 4; ++j) {
            int q = qt * 64 + tx + 16 * j;
            outp[((size_t)b * 1024 + cg) * 1024 + q] = acc[i][j];
        }
    }
}

extern "C" void kernel_launch(void* const* d_in, const int* in_sizes, int n_in,
                              void* d_out, int out_size, void* d_ws, size_t ws_size,
                              hipStream_t stream) {
    const float* src_temp   = (const float*)d_in[0];
    const float* src_search = (const float*)d_in[1];
    const float* wk_m = (const float*)d_in[2];
    const float* bk_m = (const float*)d_in[3];
    const float* wv_m = (const float*)d_in[4];
    const float* bv_m = (const float*)d_in[5];
    const float* wk_q = (const float*)d_in[6];
    const float* bk_q = (const float*)d_in[7];
    const float* wv_q = (const float*)d_in[8];
    const float* bv_q = (const float*)d_in[9];
    float* out = (float*)d_out;
    char* ws = (char*)d_ws;
    bf16* Ah = (bf16*)(ws + OFF_AHI);
    bf16* Al = (bf16*)(ws + OFF_ALO);
    bf16* Wh = (bf16*)(ws + OFF_WHI);
    bf16* Wl = (bf16*)(ws + OFF_WLO);
    float* qkeyT = (float*)(ws + OFF_QKEYT);
    float* mkeyT = (float*)(ws + OFF_MKEYT);
    float* mval  = (float*)(ws + OFF_MVAL);
    float* wattn = (float*)(ws + OFF_WATTN);

    hipLaunchKernelGGL(k_zero, dim3(1056), dim3(256), 0, stream, Ah, Al);

    // g = 1 (search): keys -> qkeyT, values -> d_out channels 512..1023
    hipLaunchKernelGGL(k_wt, dim3(27648), dim3(256), 0, stream, wk_q, wv_q, Wh, Wl);
    for (int h = 0; h < 2; ++h) {
        hipLaunchKernelGGL(k_transpose, dim3(16, 16, 8), dim3(256), 0, stream,
                           src_search + (size_t)h * 8 * 1024 * 1024, Ah, Al);
        hipLaunchKernelGGL(k_conv, dim3(64, 8), dim3(256), 0, stream,
                           Ah, Al, Wh, Wl, bk_q, bv_q, qkeyT, out, 1024, 512, h * 8);
    }
    // g = 0 (temp): keys -> mkeyT, values -> mval
    hipLaunchKernelGGL(k_wt, dim3(27648), dim3(256), 0, stream, wk_m, wv_m, Wh, Wl);
    for (int h = 0; h < 2; ++h) {
        hipLaunchKernelGGL(k_transpose, dim3(16, 16, 8), dim3(256), 0, stream,
                           src_temp + (size_t)h * 8 * 1024 * 1024, Ah, Al);
        hipLaunchKernelGGL(k_conv, dim3(64, 8), dim3(256), 0, stream,
                           Ah, Al, Wh, Wl, bk_m, bv_m, mkeyT, mval, 512, 0, h * 8);
    }

    hipLaunchKernelGGL(k_scores,  dim3(16, 16, 16), dim3(256), 0, stream, mkeyT, qkeyT, wattn);
    hipLaunchKernelGGL(k_softmax, dim3(4096),       dim3(256), 0, stream, wattn);
    hipLaunchKernelGGL(k_memv,    dim3(16, 8, 16),  dim3(256), 0, stream, mval, wattn, out);
}